// Round 3
// baseline (110.639 us; speedup 1.0000x reference)
//
#include <hip/hip_runtime.h>
#include <hip/hip_cooperative_groups.h>
#include <math.h>

namespace cg = cooperative_groups;

#define N_PROP 1000
#define N_CLS  81
#define N_FG   80
#define SCORE_THRESH 0.05f
#define NMS_THRESH   0.5f
#define DET_PER_IMG  100
#define BBOX_CLIP    4.135166556742356f   // ln(1000/16)

// d_out layout (560000 floats):
//   [0, 400000)        out5: (80*1000, 5)
//   [400000, 480000)   labels as float
//   [480000, 560000)   final mask as 0.0/1.0
#define LBL_OFF    400000
#define FIN_OFF    480000

#define NBLOCKS 160

// ws layout (bytes):
//   [0,4)              int   kept count
//   [64, 64+320000)    float probT[80][1000]  (transposed fg scores)
//   [320064, +320000)  float compact kept scores

__global__ __launch_bounds__(256)
void fused_kernel(const float* __restrict__ logits,
                  const float* __restrict__ reg,
                  const float* __restrict__ props,
                  const int* __restrict__ ihp,
                  const int* __restrict__ iwp,
                  float* __restrict__ out,
                  int* __restrict__ count,
                  float* __restrict__ probT,
                  float* __restrict__ compact)
{
    cg::grid_group grid = cg::this_grid();
    const int b = blockIdx.x;
    const int t = threadIdx.x;     // 0..255
    const int lane = t & 63;
    const int wave = t >> 6;       // 0..3

    __shared__ float sSc[N_PROP];
    __shared__ int   sIdx[N_PROP];
    __shared__ int   sPos[N_PROP];
    __shared__ float sx1[N_PROP], sy1[N_PROP], sx2[N_PROP], sy2[N_PROP];
    __shared__ float sar[N_PROP], sSc2[N_PROP];
    __shared__ int   sJdx[N_PROP];
    __shared__ unsigned char sKeep[N_PROP];
    __shared__ int   shV;
    __shared__ int   red4[4];
    __shared__ float lsc[8192];

    // ---------------- phase A: zero output, softmax -> probT ----------------
    if (b == 0 && t == 0) *count = 0;
    {
        float4 z = make_float4(0.f, 0.f, 0.f, 0.f);
        float4* o4 = (float4*)out;
        for (int i = b * 256 + t; i < 140000; i += NBLOCKS * 256) o4[i] = z;
    }
    for (int n = b * 4 + wave; n < N_PROP; n += NBLOCKS * 4) {
        const float* lrow = logits + (size_t)n * N_CLS;
        float v0 = lrow[lane];
        float v1 = (lane + 64 < N_CLS) ? lrow[lane + 64] : -INFINITY;
        float m = fmaxf(v0, v1);
        for (int off = 32; off; off >>= 1) m = fmaxf(m, __shfl_down(m, off));
        m = __shfl(m, 0);
        float e0 = expf(v0 - m);
        float e1 = (lane + 64 < N_CLS) ? expf(v1 - m) : 0.0f;
        float s = e0 + e1;
        for (int off = 32; off; off >>= 1) s += __shfl_down(s, off);
        s = __shfl(s, 0);
        // prob for class cls lives where its logit was loaded: e(cls)/s
        if (lane >= 1)           probT[(size_t)(lane - 1) * N_PROP + n] = e0 / s;
        if (lane + 64 < N_CLS)   probT[(size_t)(lane + 63) * N_PROP + n] = e1 / s;
    }
    grid.sync();

    // ---------------- phase B: per-class NMS (block b = class b) ------------
    if (b < N_FG) {
        const int c = b;
        for (int j = t; j < N_PROP; j += 256) sSc[j] = probT[(size_t)c * N_PROP + j];
        __syncthreads();

        // wave-0 ballot compaction (in place; per-chunk reads precede writes)
        if (wave == 0) {
            int V = 0;
            #pragma unroll
            for (int it = 0; it < 16; ++it) {
                int j = it * 64 + lane;
                float sc = (j < N_PROP) ? sSc[j] : -1.0f;
                bool val = (j < N_PROP) && (sc > SCORE_THRESH);
                unsigned long long mask = __ballot(val);
                int pre = __popcll(mask & ((1ULL << lane) - 1ULL));
                if (val) { sSc[V + pre] = sc; sIdx[V + pre] = j; }
                V += __popcll(mask);
            }
            if (lane == 0) shV = V;
        }
        __syncthreads();
        const int V = shV;

        // stable descending rank (ties -> lower original index)
        for (int v = t; v < V; v += 256) {
            float s = sSc[v];
            int id = sIdx[v];
            int r = 0;
            for (int u = 0; u < V; ++u) {
                float su = sSc[u];
                r += (su > s) || (su == s && sIdx[u] < id);
            }
            sPos[v] = r;
        }
        __syncthreads();

        // gather into sorted slots + decode boxes (valid entries only)
        const float W1 = (float)iwp[0] - 1.0f;
        const float H1 = (float)ihp[0] - 1.0f;
        for (int v = t; v < V; v += 256) {
            int r = sPos[v];
            int j = sIdx[v];
            float4 pr = *(const float4*)(props + (size_t)j * 4);
            float w  = pr.z - pr.x + 1.0f;
            float h  = pr.w - pr.y + 1.0f;
            float cx = pr.x + 0.5f * w;
            float cy = pr.y + 0.5f * h;
            float4 rr = *(const float4*)(reg + ((size_t)j * N_CLS + (c + 1)) * 4);
            float dx = rr.x / 10.0f;
            float dy = rr.y / 10.0f;
            float dw = fminf(rr.z / 5.0f, BBOX_CLIP);
            float dh = fminf(rr.w / 5.0f, BBOX_CLIP);
            float pcx = dx * w + cx;
            float pcy = dy * h + cy;
            float pw = expf(dw) * w;
            float ph = expf(dh) * h;
            float bx1 = pcx - 0.5f * pw;
            float by1 = pcy - 0.5f * ph;
            float bx2 = pcx + 0.5f * pw - 1.0f;
            float by2 = pcy + 0.5f * ph - 1.0f;
            bx1 = fminf(fmaxf(bx1, 0.0f), W1);
            bx2 = fminf(fmaxf(bx2, 0.0f), W1);
            by1 = fminf(fmaxf(by1, 0.0f), H1);
            by2 = fminf(fmaxf(by2, 0.0f), H1);
            sx1[r] = bx1; sy1[r] = by1; sx2[r] = bx2; sy2[r] = by2;
            sar[r] = (bx2 - bx1 + 1.0f) * (by2 - by1 + 1.0f);
            sSc2[r] = sSc[v];
            sJdx[r] = j;
            sKeep[r] = 1;
        }
        __syncthreads();

        // sequential suppression (reference's sorted scan)
        for (int r = 0; r < V; ++r) {
            if (sKeep[r]) {
                const float X1 = sx1[r], Y1 = sy1[r], X2 = sx2[r], Y2 = sy2[r], A = sar[r];
                for (int v = r + 1 + t; v < V; v += 256) {
                    if (sKeep[v]) {
                        float iw = fminf(X2, sx2[v]) - fmaxf(X1, sx1[v]) + 1.0f;
                        float ih = fminf(Y2, sy2[v]) - fmaxf(Y1, sy1[v]) + 1.0f;
                        iw = fmaxf(iw, 0.0f);
                        ih = fmaxf(ih, 0.0f);
                        float inter = iw * ih;
                        float iou = inter / (A + sar[v] - inter);
                        if (iou > NMS_THRESH) sKeep[v] = 0;   // NaN-safe, like ref
                    }
                }
            }
            __syncthreads();
        }

        // append kept scores for the global top-k threshold
        for (int v = t; v < V; v += 256) {
            if (sKeep[v]) {
                int pos = atomicAdd(count, 1);
                compact[pos] = sSc2[v];
            }
        }
    }
    grid.sync();

    // ------- phase C: every class block redundantly computes threshold ------
    // ------- phase D: write final detections from persistent LDS ------------
    if (b < N_FG) {
        const int n = *count;
        float th = 0.0f;   // all kept scores > 0.05 > 0 -> pass-all
        if (n > DET_PER_IMG) {
            const bool useL = (n <= 8192);
            if (useL) {
                for (int i = t; i < n; i += 256) lsc[i] = compact[i];
                __syncthreads();
            }
            unsigned lo = 0u, hi = 0x40000000u;   // scores in (0.05, 1.0]
            while (hi - lo > 1u) {
                unsigned mid = lo + ((hi - lo) >> 1);
                float mv = __uint_as_float(mid);
                int cnt = 0;
                if (useL) { for (int i = t; i < n; i += 256) cnt += (lsc[i] >= mv) ? 1 : 0; }
                else      { for (int i = t; i < n; i += 256) cnt += (compact[i] >= mv) ? 1 : 0; }
                for (int off = 32; off; off >>= 1) cnt += __shfl_down(cnt, off);
                if (lane == 0) red4[wave] = cnt;
                __syncthreads();
                int total = red4[0] + red4[1] + red4[2] + red4[3];
                __syncthreads();
                if (total >= DET_PER_IMG + 1) lo = mid; else hi = mid;
            }
            th = __uint_as_float(lo);
        }
        const int V = shV;
        for (int r = t; r < V; r += 256) {
            if (sKeep[r] && sSc2[r] >= th) {
                size_t row = (size_t)b * N_PROP + sJdx[r];
                out[row * 5 + 0] = sx1[r];
                out[row * 5 + 1] = sy1[r];
                out[row * 5 + 2] = sx2[r];
                out[row * 5 + 3] = sy2[r];
                out[row * 5 + 4] = sSc2[r];
                out[LBL_OFF + row] = (float)(b + 1);
                out[FIN_OFF + row] = 1.0f;
            }
        }
    }
}

extern "C" void kernel_launch(void* const* d_in, const int* in_sizes, int n_in,
                              void* d_out, int out_size, void* d_ws, size_t ws_size,
                              hipStream_t stream) {
    const float* logits = (const float*)d_in[0];
    const float* reg    = (const float*)d_in[1];
    const float* props  = (const float*)d_in[2];
    const int*   ihp    = (const int*)d_in[3];
    const int*   iwp    = (const int*)d_in[4];
    float* out = (float*)d_out;

    char* ws = (char*)d_ws;
    int*   count   = (int*)(ws + 0);
    float* probT   = (float*)(ws + 64);
    float* compact = (float*)(ws + 320064);

    void* args[] = { (void*)&logits, (void*)&reg, (void*)&props, (void*)&ihp, (void*)&iwp,
                     (void*)&out, (void*)&count, (void*)&probT, (void*)&compact };
    hipLaunchCooperativeKernel((void*)fused_kernel, dim3(NBLOCKS), dim3(256), args, 0, stream);
}

// Round 4
// 70.432 us; speedup vs baseline: 1.5709x; 1.5709x over previous
//
#include <hip/hip_runtime.h>
#include <math.h>

#define N_PROP 1000
#define N_CLS  81
#define N_FG   80
#define SCORE_THRESH 0.05f
#define NMS_THRESH   0.5f
#define DET_PER_IMG  100
#define BBOX_CLIP    4.135166556742356f   // ln(1000/16)

// d_out layout (560000 floats):
//   [0, 400000)        out5: (80*1000, 5)
//   [400000, 480000)   labels as float
//   [480000, 560000)   final mask as 0.0/1.0
#define LBL_OFF    400000
#define FIN_OFF    480000

// ws layout (bytes):
//   [0,4)               int   survivor count
//   [64, 320064)        float probT[80][1000]
//   [320064, 640064)    float compact survivor scores
//   [640064, 960064)    int   survivor row ids (c*1000+j)

// ---------------- K1: zero output + softmax -> probT (transposed) ----------
__global__ __launch_bounds__(256)
void softmax_zero_kernel(const float* __restrict__ logits,
                         float* __restrict__ out,
                         int* __restrict__ count,
                         float* __restrict__ probT) {
    const int b = blockIdx.x;
    const int t = threadIdx.x;
    const int lane = t & 63;
    const int wave = t >> 6;
    if (b == 0 && t == 0) *count = 0;

    float4 z = make_float4(0.f, 0.f, 0.f, 0.f);
    float4* o4 = (float4*)out;
    for (int i = b * 256 + t; i < 140000; i += 250 * 256) o4[i] = z;

    const int n = b * 4 + wave;           // 250 blocks * 4 waves = 1000
    if (n < N_PROP) {
        const float* lrow = logits + (size_t)n * N_CLS;
        float v0 = lrow[lane];
        float v1 = (lane + 64 < N_CLS) ? lrow[lane + 64] : -INFINITY;
        float m = fmaxf(v0, v1);
        for (int off = 32; off; off >>= 1) m = fmaxf(m, __shfl_down(m, off));
        m = __shfl(m, 0);
        float e0 = expf(v0 - m);
        float e1 = (lane + 64 < N_CLS) ? expf(v1 - m) : 0.0f;
        float s = e0 + e1;
        for (int off = 32; off; off >>= 1) s += __shfl_down(s, off);
        s = __shfl(s, 0);
        if (lane >= 1)          probT[(size_t)(lane - 1) * N_PROP + n] = e0 / s;
        if (lane + 64 < N_CLS)  probT[(size_t)(lane + 63) * N_PROP + n] = e1 / s;
    }
}

// ---------------- K2: per-class NMS, write kept boxes + survivor list ------
__global__ __launch_bounds__(256)
void nms_kernel(const float* __restrict__ probT,
                const float* __restrict__ props,
                const float* __restrict__ reg,
                const int* __restrict__ ihp,
                const int* __restrict__ iwp,
                float* __restrict__ out,
                int* __restrict__ count,
                float* __restrict__ compact,
                int* __restrict__ svRow) {
    const int c = blockIdx.x;     // 0..79
    const int t = threadIdx.x;    // 0..255
    const int lane = t & 63;
    const int wave = t >> 6;

    __shared__ float sSc[N_PROP];
    __shared__ int   sIdx[N_PROP];
    __shared__ int   sPos[N_PROP];
    __shared__ float sx1[N_PROP], sy1[N_PROP], sx2[N_PROP], sy2[N_PROP];
    __shared__ float sar[N_PROP], sSc2[N_PROP];
    __shared__ int   sJdx[N_PROP];
    __shared__ unsigned char sKeep[N_PROP];
    __shared__ int   shV;

    for (int j = t; j < N_PROP; j += 256) sSc[j] = probT[(size_t)c * N_PROP + j];
    __syncthreads();

    // wave-0 ballot compaction (in place; reads of a chunk precede its writes)
    if (wave == 0) {
        int V = 0;
        #pragma unroll
        for (int it = 0; it < 16; ++it) {
            int j = it * 64 + lane;
            float sc = (j < N_PROP) ? sSc[j] : -1.0f;
            bool val = (j < N_PROP) && (sc > SCORE_THRESH);
            unsigned long long mask = __ballot(val);
            int pre = __popcll(mask & ((1ULL << lane) - 1ULL));
            if (val) { sSc[V + pre] = sc; sIdx[V + pre] = j; }
            V += __popcll(mask);
        }
        if (lane == 0) shV = V;
    }
    __syncthreads();
    const int V = shV;

    // stable descending rank (ties -> lower original index)
    for (int v = t; v < V; v += 256) {
        float s = sSc[v];
        int id = sIdx[v];
        int r = 0;
        for (int u = 0; u < V; ++u) {
            float su = sSc[u];
            r += (su > s) || (su == s && sIdx[u] < id);
        }
        sPos[v] = r;
    }
    __syncthreads();

    // gather into sorted slots + decode boxes (valid entries only)
    const float W1 = (float)iwp[0] - 1.0f;
    const float H1 = (float)ihp[0] - 1.0f;
    for (int v = t; v < V; v += 256) {
        int r = sPos[v];
        int j = sIdx[v];
        float4 pr = *(const float4*)(props + (size_t)j * 4);
        float w  = pr.z - pr.x + 1.0f;
        float h  = pr.w - pr.y + 1.0f;
        float cx = pr.x + 0.5f * w;
        float cy = pr.y + 0.5f * h;
        float4 rr = *(const float4*)(reg + ((size_t)j * N_CLS + (c + 1)) * 4);
        float dx = rr.x / 10.0f;
        float dy = rr.y / 10.0f;
        float dw = fminf(rr.z / 5.0f, BBOX_CLIP);
        float dh = fminf(rr.w / 5.0f, BBOX_CLIP);
        float pcx = dx * w + cx;
        float pcy = dy * h + cy;
        float pw = expf(dw) * w;
        float ph = expf(dh) * h;
        float bx1 = pcx - 0.5f * pw;
        float by1 = pcy - 0.5f * ph;
        float bx2 = pcx + 0.5f * pw - 1.0f;
        float by2 = pcy + 0.5f * ph - 1.0f;
        bx1 = fminf(fmaxf(bx1, 0.0f), W1);
        bx2 = fminf(fmaxf(bx2, 0.0f), W1);
        by1 = fminf(fmaxf(by1, 0.0f), H1);
        by2 = fminf(fmaxf(by2, 0.0f), H1);
        sx1[r] = bx1; sy1[r] = by1; sx2[r] = bx2; sy2[r] = by2;
        sar[r] = (bx2 - bx1 + 1.0f) * (by2 - by1 + 1.0f);
        sSc2[r] = sSc[v];
        sJdx[r] = j;
        sKeep[r] = 1;
    }
    __syncthreads();

    // sequential suppression (reference's sorted greedy scan)
    for (int r = 0; r < V; ++r) {
        if (sKeep[r]) {
            const float X1 = sx1[r], Y1 = sy1[r], X2 = sx2[r], Y2 = sy2[r], A = sar[r];
            for (int v = r + 1 + t; v < V; v += 256) {
                if (sKeep[v]) {
                    float iw = fminf(X2, sx2[v]) - fmaxf(X1, sx1[v]) + 1.0f;
                    float ih = fminf(Y2, sy2[v]) - fmaxf(Y1, sy1[v]) + 1.0f;
                    iw = fmaxf(iw, 0.0f);
                    ih = fmaxf(ih, 0.0f);
                    float inter = iw * ih;
                    float iou = inter / (A + sar[v] - inter);
                    if (iou > NMS_THRESH) sKeep[v] = 0;   // NaN-safe, like ref
                }
            }
        }
        __syncthreads();
    }

    // write kept boxes to out5 + append survivor (score,row)
    for (int v = t; v < V; v += 256) {
        if (sKeep[v]) {
            size_t row = (size_t)c * N_PROP + sJdx[v];
            out[row * 5 + 0] = sx1[v];
            out[row * 5 + 1] = sy1[v];
            out[row * 5 + 2] = sx2[v];
            out[row * 5 + 3] = sy2[v];
            out[row * 5 + 4] = sSc2[v];
            int pos = atomicAdd(count, 1);
            compact[pos] = sSc2[v];
            svRow[pos] = (int)row;
        }
    }
}

// ---------------- K3: image threshold + finalize survivors -----------------
__global__ __launch_bounds__(256)
void finalize_kernel(float* __restrict__ out,
                     const float* __restrict__ compact,
                     const int* __restrict__ svRow,
                     const int* __restrict__ count) {
    __shared__ float lsc[8192];
    __shared__ int red4[4];
    const int n = *count;
    const int t = threadIdx.x;
    const int lane = t & 63;
    const int wave = t >> 6;

    float th = 0.0f;   // kept scores all > 0.05 > 0 -> pass-all when n <= 100
    if (n > DET_PER_IMG) {
        const bool useL = (n <= 8192);
        if (useL) {
            for (int i = t; i < n; i += 256) lsc[i] = compact[i];
            __syncthreads();
        }
        unsigned lo = 0u, hi = 0x40000000u;   // scores in (0.05, 1.0]
        while (hi - lo > 1u) {
            unsigned mid = lo + ((hi - lo) >> 1);
            float mv = __uint_as_float(mid);
            int cnt = 0;
            if (useL) { for (int i = t; i < n; i += 256) cnt += (lsc[i] >= mv) ? 1 : 0; }
            else      { for (int i = t; i < n; i += 256) cnt += (compact[i] >= mv) ? 1 : 0; }
            for (int off = 32; off; off >>= 1) cnt += __shfl_down(cnt, off);
            if (lane == 0) red4[wave] = cnt;
            __syncthreads();
            int total = red4[0] + red4[1] + red4[2] + red4[3];
            __syncthreads();
            if (total >= DET_PER_IMG + 1) lo = mid; else hi = mid;
        }
        th = __uint_as_float(lo);
    }

    for (int i = blockIdx.x * 256 + t; i < n; i += gridDim.x * 256) {
        float sc = compact[i];
        int row = svRow[i];
        if (sc >= th) {
            int c = row / N_PROP;
            out[LBL_OFF + row] = (float)(c + 1);
            out[FIN_OFF + row] = 1.0f;
        } else {
            size_t o = (size_t)row * 5;
            out[o + 0] = 0.0f;
            out[o + 1] = 0.0f;
            out[o + 2] = 0.0f;
            out[o + 3] = 0.0f;
            out[o + 4] = 0.0f;
        }
    }
}

extern "C" void kernel_launch(void* const* d_in, const int* in_sizes, int n_in,
                              void* d_out, int out_size, void* d_ws, size_t ws_size,
                              hipStream_t stream) {
    const float* logits = (const float*)d_in[0];
    const float* reg    = (const float*)d_in[1];
    const float* props  = (const float*)d_in[2];
    const int*   ihp    = (const int*)d_in[3];
    const int*   iwp    = (const int*)d_in[4];
    float* out = (float*)d_out;

    char* ws = (char*)d_ws;
    int*   count   = (int*)(ws + 0);
    float* probT   = (float*)(ws + 64);
    float* compact = (float*)(ws + 320064);
    int*   svRow   = (int*)(ws + 640064);

    softmax_zero_kernel<<<250, 256, 0, stream>>>(logits, out, count, probT);
    nms_kernel<<<N_FG, 256, 0, stream>>>(probT, props, reg, ihp, iwp, out, count, compact, svRow);
    finalize_kernel<<<16, 256, 0, stream>>>(out, compact, svRow, count);
}